// Round 2
// baseline (1132.754 us; speedup 1.0000x reference)
//
#include <hip/hip_runtime.h>
#include <hip/hip_bf16.h>

// ---- JAX PRNG variant switches ----
// JAX_PARTITIONABLE: 1 = jax_threefry_partitionable=True (modern default)
// PART_MODE: 0 = bits1 (word0), 1 = bits2 (word1), 2 = bits1^bits2
#define JAX_PARTITIONABLE 1
#define PART_MODE 2

#define HW 4096      // 64*64 pixels
#define NS 12        // num_steps
#define PPB 49152    // HW*NS points per batch element

__host__ __device__ __forceinline__ void tf2x32(unsigned k0, unsigned k1,
                                                unsigned x0, unsigned x1,
                                                unsigned &o0, unsigned &o1) {
  unsigned ks2 = k0 ^ k1 ^ 0x1BD11BDAu;
  unsigned v0 = x0 + k0, v1 = x1 + k1;
#define TFR(r) do { v0 += v1; v1 = (v1 << (r)) | (v1 >> (32 - (r))); v1 ^= v0; } while (0)
  TFR(13); TFR(15); TFR(26); TFR(6);   v0 += k1;  v1 += ks2 + 1u;
  TFR(17); TFR(29); TFR(16); TFR(24);  v0 += ks2; v1 += k0 + 2u;
  TFR(13); TFR(15); TFR(26); TFR(6);   v0 += k0;  v1 += k1 + 3u;
  TFR(17); TFR(29); TFR(16); TFR(24);  v0 += k1;  v1 += ks2 + 4u;
  TFR(13); TFR(15); TFR(26); TFR(6);   v0 += ks2; v1 += k0 + 5u;
#undef TFR
  o0 = v0; o1 = v1;
}

__device__ __forceinline__ float jax_uniform(unsigned k0, unsigned k1,
                                             unsigned idx, unsigned total) {
  unsigned o0, o1, bits;
#if JAX_PARTITIONABLE
  tf2x32(k0, k1, 0u, idx, o0, o1);
#if PART_MODE == 0
  bits = o0;
#elif PART_MODE == 1
  bits = o1;
#else
  bits = o0 ^ o1;
#endif
#else
  unsigned half = total >> 1;
  if (idx < half) { tf2x32(k0, k1, idx, idx + half, o0, o1); bits = o0; }
  else            { tf2x32(k0, k1, idx - half, idx, o0, o1); bits = o1; }
#endif
  return __uint_as_float(0x3f800000u | (bits >> 9)) - 1.0f;
}

__device__ __forceinline__ void pixel_dir(int n, float &dx, float &dy, float &dz) {
  int pi = n >> 6, pj = n & 63;
  float x = -1.0f + (float)pj * (2.0f / 63.0f);
  float y =  1.0f - (float)pi * (2.0f / 63.0f);
  float zc = -1.0f / tanf(0.10471975511965978f);  // deg2rad(12)/2
  float inv = 1.0f / sqrtf(x * x + y * y + zc * zc);
  dx = x * inv; dy = y * inv; dz = zc * inv;
}

// ---------------- mapping network: z(256) -> freqs/phases (768 each) ---------
__global__ __launch_bounds__(256) void k_map(const float *z, const float *w0, const float *b0,
                                             const float *w1, const float *b1,
                                             const float *w2, const float *b2,
                                             float *freqs, float *phases) {
  __shared__ float zl[256], h1[256], h2[256];
  int b = blockIdx.x, t = threadIdx.x;
  zl[t] = z[b * 256 + t];
  __syncthreads();
  float acc = b0[t];
  for (int k = 0; k < 256; k++) acc += zl[k] * w0[k * 256 + t];
  h1[t] = (acc >= 0.0f) ? acc : 0.2f * acc;
  __syncthreads();
  acc = b1[t];
  for (int k = 0; k < 256; k++) acc += h1[k] * w1[k * 256 + t];
  h2[t] = (acc >= 0.0f) ? acc : 0.2f * acc;
  __syncthreads();
  float a6[6];
#pragma unroll
  for (int m = 0; m < 6; m++) a6[m] = b2[t + m * 256];
  for (int k = 0; k < 256; k++) {
    float h = h2[k];
#pragma unroll
    for (int m = 0; m < 6; m++) a6[m] += h * w2[k * 1536 + t + m * 256];
  }
#pragma unroll
  for (int m = 0; m < 6; m++) {
    int o = t + m * 256;
    if (o < 768) freqs[b * 768 + o] = a6[m] * 15.0f + 30.0f;
    else         phases[b * 768 + (o - 768)] = a6[m];
  }
}

// ---------------- coarse rays: perturbed z + transformed points --------------
__global__ __launch_bounds__(256) void k_rays(const float *c2w, float *zv, float *pts,
                                              unsigned kp0, unsigned kp1, int npts) {
  int e = blockIdx.x * 256 + threadIdx.x;
  if (e >= npts) return;
  int b = e / PPB, r = e % PPB, n = r / NS, s = r % NS;
  float dx, dy, dz; pixel_dir(n, dx, dy, dz);
  float delta = (1.12f - 0.88f) / 11.0f;
  float u = jax_uniform(kp0, kp1, (unsigned)e, (unsigned)npts);
  float zval = 0.88f + (float)s * delta + (u - 0.5f) * (float)(0.24 / 11.0);
  zv[e] = zval;
  float px = dx * zval, py = dy * zval, pz = dz * zval;
  const float *M = c2w + b * 16;
  float m[12];
#pragma unroll
  for (int i = 0; i < 12; i++) m[i] = M[i];
  pts[e * 3 + 0] = m[0] * px + m[1] * py + m[2] * pz + m[3];
  pts[e * 3 + 1] = m[4] * px + m[5] * py + m[6] * pz + m[7];
  pts[e * 3 + 2] = m[8] * px + m[9] * py + m[10] * pz + m[11];
}

// ---------------- SIREN forward: 32 points/block, thread = hidden dim --------
__global__ __launch_bounds__(128) void k_siren(const float *pts, const float *freqs,
                                               const float *phases,
                                               const float *fw, const float *fb,
                                               const float *hw, const float *hb,
                                               const float *ow, const float *ob,
                                               float *outp) {
  __shared__ __align__(16) float xl[128 * 36];  // [k][p], pitch 36 (144B, 16B-aligned rows)
  __shared__ float ptl[96];
  __shared__ float owl[512];
  __shared__ float obl[4];
  int t = threadIdx.x;
  int base = blockIdx.x * 32;
  int b = base / PPB;
  if (t < 96) ptl[t] = pts[base * 3 + t];
#pragma unroll
  for (int q = 0; q < 4; q++) owl[t + 128 * q] = ow[t + 128 * q];
  if (t < 4) obl[t] = ob[t];
  float fq = freqs[b * 768 + t], ph = phases[b * 768 + t];
  float w0 = fw[t];
  float w1 = fw[128 + t];
  float w2 = fw[256 + t];
  float fbv = fb[t];
  __syncthreads();
#pragma unroll
  for (int p = 0; p < 32; p++) {
    float pre = ptl[p * 3] * w0 + ptl[p * 3 + 1] * w1 + ptl[p * 3 + 2] * w2 + fbv;
    xl[t * 36 + p] = sinf(fq * pre + ph);
  }
  __syncthreads();
#pragma unroll 1
  for (int L = 1; L < 6; L++) {
    float fql = freqs[b * 768 + L * 128 + t], phl = phases[b * 768 + L * 128 + t];
    const float *Wg = hw + (L - 1) * 16384 + t;
    float bias = hb[(L - 1) * 128 + t];
    float acc[32];
#pragma unroll
    for (int p = 0; p < 32; p++) acc[p] = bias;
#pragma unroll 4
    for (int k = 0; k < 128; k++) {
      float wv = Wg[k * 128];
      const float4 *xr = (const float4 *)&xl[k * 36];
#pragma unroll
      for (int q = 0; q < 8; q++) {
        float4 xv = xr[q];
        acc[4 * q + 0] += xv.x * wv;
        acc[4 * q + 1] += xv.y * wv;
        acc[4 * q + 2] += xv.z * wv;
        acc[4 * q + 3] += xv.w * wv;
      }
    }
    __syncthreads();
#pragma unroll
    for (int p = 0; p < 32; p++) xl[t * 36 + p] = sinf(fql * acc[p] + phl);
    __syncthreads();
  }
  int p = t >> 2, c = t & 3;
  float acc = obl[c];
#pragma unroll 4
  for (int k = 0; k < 128; k++) acc += xl[k * 36 + p] * owl[k * 4 + c];
  if (c < 3) acc = 1.0f / (1.0f + expf(-acc));
  outp[(base + p) * 4 + c] = acc;
}

// ---------------- coarse weights -> sample_pdf -> fine points ----------------
__global__ __launch_bounds__(256) void k_pdf(const float *zv, const float *coutb,
                                             const float *c2w, float *fz, float *fpts,
                                             unsigned kq0, unsigned kq1, int nrays) {
  int ray = blockIdx.x * 256 + threadIdx.x;
  if (ray >= nrays) return;
  int b = ray / HW, n = ray % HW;
  float z[12];
#pragma unroll
  for (int s = 0; s < 12; s++) z[s] = zv[ray * 12 + s];
  float w[12]; float T = 1.0f;
#pragma unroll
  for (int s = 0; s < 12; s++) {
    float d = (s < 11) ? z[s + 1] - z[s] : 1e10f;
    float sg = coutb[(ray * 12 + s) * 4 + 3];
    float a = 1.0f - expf(-d * fmaxf(sg, 0.0f));
    w[s] = a * T;
    T *= 1.0f - a + 1e-10f;
  }
  float zmid[11];
#pragma unroll
  for (int i = 0; i < 11; i++) zmid[i] = 0.5f * (z[i] + z[i + 1]);
  float pw[10], sum = 0.0f;
#pragma unroll
  for (int i = 0; i < 10; i++) { pw[i] = w[i + 1] + 1e-5f; sum += pw[i]; }
  float cdf[11]; cdf[0] = 0.0f; float cacc = 0.0f;
#pragma unroll
  for (int i = 0; i < 10; i++) { cacc += pw[i] / sum; cdf[i + 1] = cacc; }

  const float *M = c2w + b * 16;
  float m[12];
#pragma unroll
  for (int i = 0; i < 12; i++) m[i] = M[i];
  float dx, dy, dz; pixel_dir(n, dx, dy, dz);
  float tdx = m[0] * dx + m[1] * dy + m[2] * dz;
  float tdy = m[4] * dx + m[5] * dy + m[6] * dz;
  float tdz = m[8] * dx + m[9] * dy + m[10] * dz;
  float ox = m[3], oy = m[7], oz = m[11];

#pragma unroll
  for (int t = 0; t < 12; t++) {
    float u = jax_uniform(kq0, kq1, (unsigned)(ray * 12 + t), (unsigned)(nrays * 12));
    int ind = 0;
#pragma unroll
    for (int i = 0; i < 11; i++) ind += (cdf[i] <= u) ? 1 : 0;  // searchsorted 'right'
    int below = ind - 1; below = below < 0 ? 0 : (below > 10 ? 10 : below);
    int above = ind > 10 ? 10 : ind;
    float cl = 0.f, ch = 0.f, blo = 0.f, bhi = 0.f;
#pragma unroll
    for (int i = 0; i < 11; i++) {
      if (i == below) { cl = cdf[i]; blo = zmid[i]; }
      if (i == above) { ch = cdf[i]; bhi = zmid[i]; }
    }
    float den = ch - cl; if (den < 1e-8f) den = 1.0f;
    float f = blo + (u - cl) / den * (bhi - blo);
    fz[ray * 12 + t] = f;
    fpts[(ray * 12 + t) * 3 + 0] = ox + tdx * f;
    fpts[(ray * 12 + t) * 3 + 1] = oy + tdy * f;
    fpts[(ray * 12 + t) * 3 + 2] = oz + tdz * f;
  }
}

// ---------------- merge (stable sort by z), final integration ----------------
__global__ __launch_bounds__(64) void k_final(const float *zv, const float *fz,
                                              const float *coutb, const float *foutb,
                                              float *outp, int B) {
  __shared__ float L[120 * 64];   // per-thread column: z[24], sig[24], rgb[3][24]
  __shared__ int inv[24 * 64];
  int t = threadIdx.x;
  int ray = blockIdx.x * 64 + t;
  int b = ray / HW, n = ray % HW;
#define SL(e) L[(e) * 64 + t]
  float zr[24];
#pragma unroll
  for (int s = 0; s < 12; s++) {
    float zfv = fz[ray * 12 + s], zcv = zv[ray * 12 + s];
    zr[s] = zfv; zr[12 + s] = zcv;   // concat order: fine first, then coarse
    SL(s) = zfv; SL(12 + s) = zcv;
    SL(24 + s)      = foutb[(ray * 12 + s) * 4 + 3];
    SL(24 + 12 + s) = coutb[(ray * 12 + s) * 4 + 3];
#pragma unroll
    for (int c = 0; c < 3; c++) {
      SL(48 + c * 24 + s)      = foutb[(ray * 12 + s) * 4 + c];
      SL(48 + c * 24 + 12 + s) = coutb[(ray * 12 + s) * 4 + c];
    }
  }
  // stable ranks (ties broken by original index) == JAX stable argsort
#pragma unroll
  for (int i = 0; i < 24; i++) {
    int rank = 0;
#pragma unroll
    for (int j = 0; j < 24; j++)
      rank += (zr[j] < zr[i] || (zr[j] == zr[i] && j < i)) ? 1 : 0;
    inv[rank * 64 + t] = i;
  }
  float Tacc = 1.0f, r0 = 0.f, r1 = 0.f, r2 = 0.f, df = 0.f;
  int icur = inv[0 * 64 + t];
  float zcur = SL(icur);
  for (int r = 0; r < 24; r++) {
    int inext = 0; float znext = 0.f;
    if (r < 23) { inext = inv[(r + 1) * 64 + t]; znext = SL(inext); }
    float d = (r < 23) ? znext - zcur : 1e10f;
    float sg = SL(24 + icur);
    float a = 1.0f - expf(-d * fmaxf(sg, 0.0f));
    float wt = a * Tacc;
    Tacc *= 1.0f - a + 1e-10f;
    r0 += wt * SL(48 + icur);
    r1 += wt * SL(48 + 24 + icur);
    r2 += wt * SL(48 + 48 + icur);
    df += wt * zcur;
    icur = inext; zcur = znext;
  }
#undef SL
  int pi = n >> 6, pj = n & 63;
  float x = -1.0f + (float)pj * (2.0f / 63.0f);
  float y =  1.0f - (float)pi * (2.0f / 63.0f);
  float zc = -1.0f / tanf(0.10471975511965978f);
  float invn = 1.0f / sqrtf(x * x + y * y + zc * zc);
  float mdz = -zc * invn;  // -rays_d.z (positive)
  outp[(b * 3 + 0) * HW + n] = r0 * 2.0f - 1.0f;
  outp[(b * 3 + 1) * HW + n] = r1 * 2.0f - 1.0f;
  outp[(b * 3 + 2) * HW + n] = r2 * 2.0f - 1.0f;
  outp[B * 3 * HW + ray] = df * mdz;
}

extern "C" void kernel_launch(void *const *d_in, const int *in_sizes, int n_in,
                              void *d_out, int out_size, void *d_ws, size_t ws_size,
                              hipStream_t stream) {
  const float *z   = (const float *)d_in[0];
  const float *c2w = (const float *)d_in[1];
  const float *mw0 = (const float *)d_in[2];
  const float *mb0 = (const float *)d_in[3];
  const float *mw1 = (const float *)d_in[4];
  const float *mb1 = (const float *)d_in[5];
  const float *mw2 = (const float *)d_in[6];
  const float *mb2 = (const float *)d_in[7];
  const float *fw  = (const float *)d_in[8];
  const float *fb  = (const float *)d_in[9];
  const float *hw  = (const float *)d_in[10];
  const float *hb  = (const float *)d_in[11];
  const float *ow  = (const float *)d_in[12];
  const float *ob  = (const float *)d_in[13];
  int B = in_sizes[0] / 256;
  int npts = B * PPB;
  int nrays = B * HW;

  float *ws     = (float *)d_ws;
  float *freqs  = ws;
  float *phases = freqs + (size_t)B * 768;
  float *zv     = phases + (size_t)B * 768;
  float *cpts   = zv + npts;
  float *coutb  = cpts + (size_t)npts * 3;
  float *fzv    = coutb + (size_t)npts * 4;
  float *fpts   = fzv + npts;
  float *foutb  = fpts + (size_t)npts * 3;

  // key(42) = [0,42]; split -> k_pert, k_pdf
  unsigned kp0, kp1, kq0, kq1;
#if JAX_PARTITIONABLE
  { unsigned o0, o1;
    tf2x32(0u, 42u, 0u, 0u, o0, o1); kp0 = o0; kp1 = o1;
    tf2x32(0u, 42u, 0u, 1u, o0, o1); kq0 = o0; kq1 = o1; }
#else
  { unsigned a0, a1, c0, c1;
    tf2x32(0u, 42u, 0u, 2u, a0, a1);
    tf2x32(0u, 42u, 1u, 3u, c0, c1);
    kp0 = a0; kp1 = c0; kq0 = a1; kq1 = c1; }
#endif

  k_map<<<B, 256, 0, stream>>>(z, mw0, mb0, mw1, mb1, mw2, mb2, freqs, phases);
  k_rays<<<(npts + 255) / 256, 256, 0, stream>>>(c2w, zv, cpts, kp0, kp1, npts);
  k_siren<<<npts / 32, 128, 0, stream>>>(cpts, freqs, phases, fw, fb, hw, hb, ow, ob, coutb);
  k_pdf<<<(nrays + 255) / 256, 256, 0, stream>>>(zv, coutb, c2w, fzv, fpts, kq0, kq1, nrays);
  k_siren<<<npts / 32, 128, 0, stream>>>(fpts, freqs, phases, fw, fb, hw, hb, ow, ob, foutb);
  k_final<<<nrays / 64, 64, 0, stream>>>(zv, fzv, coutb, foutb, (float *)d_out, B);
}

// Round 3
// 775.226 us; speedup vs baseline: 1.4612x; 1.4612x over previous
//
#include <hip/hip_runtime.h>
#include <hip/hip_bf16.h>

// ---- JAX PRNG variant switches (verified passing in R2) ----
#define JAX_PARTITIONABLE 1
#define PART_MODE 2   // bits = o0 ^ o1

#define HW 4096      // 64*64 pixels
#define NS 12        // num_steps
#define PPB 49152    // HW*NS points per batch element

__host__ __device__ __forceinline__ void tf2x32(unsigned k0, unsigned k1,
                                                unsigned x0, unsigned x1,
                                                unsigned &o0, unsigned &o1) {
  unsigned ks2 = k0 ^ k1 ^ 0x1BD11BDAu;
  unsigned v0 = x0 + k0, v1 = x1 + k1;
#define TFR(r) do { v0 += v1; v1 = (v1 << (r)) | (v1 >> (32 - (r))); v1 ^= v0; } while (0)
  TFR(13); TFR(15); TFR(26); TFR(6);   v0 += k1;  v1 += ks2 + 1u;
  TFR(17); TFR(29); TFR(16); TFR(24);  v0 += ks2; v1 += k0 + 2u;
  TFR(13); TFR(15); TFR(26); TFR(6);   v0 += k0;  v1 += k1 + 3u;
  TFR(17); TFR(29); TFR(16); TFR(24);  v0 += k1;  v1 += ks2 + 4u;
  TFR(13); TFR(15); TFR(26); TFR(6);   v0 += ks2; v1 += k0 + 5u;
#undef TFR
  o0 = v0; o1 = v1;
}

__device__ __forceinline__ float jax_uniform(unsigned k0, unsigned k1,
                                             unsigned idx, unsigned total) {
  unsigned o0, o1, bits;
#if JAX_PARTITIONABLE
  tf2x32(k0, k1, 0u, idx, o0, o1);
#if PART_MODE == 0
  bits = o0;
#elif PART_MODE == 1
  bits = o1;
#else
  bits = o0 ^ o1;
#endif
#else
  unsigned half = total >> 1;
  if (idx < half) { tf2x32(k0, k1, idx, idx + half, o0, o1); bits = o0; }
  else            { tf2x32(k0, k1, idx - half, idx, o0, o1); bits = o1; }
#endif
  return __uint_as_float(0x3f800000u | (bits >> 9)) - 1.0f;
}

__device__ __forceinline__ void pixel_dir(int n, float &dx, float &dy, float &dz) {
  int pi = n >> 6, pj = n & 63;
  float x = -1.0f + (float)pj * (2.0f / 63.0f);
  float y =  1.0f - (float)pi * (2.0f / 63.0f);
  float zc = -1.0f / tanf(0.10471975511965978f);  // deg2rad(12)/2
  float inv = 1.0f / sqrtf(x * x + y * y + zc * zc);
  dx = x * inv; dy = y * inv; dz = zc * inv;
}

// ---------------- mapping network: z(256) -> freqs/phases (768 each) ---------
__global__ __launch_bounds__(256) void k_map(const float *z, const float *w0, const float *b0,
                                             const float *w1, const float *b1,
                                             const float *w2, const float *b2,
                                             float *freqs, float *phases) {
  __shared__ float zl[256], h1[256], h2[256];
  int b = blockIdx.x, t = threadIdx.x;
  zl[t] = z[b * 256 + t];
  __syncthreads();
  float acc = b0[t];
  for (int k = 0; k < 256; k++) acc += zl[k] * w0[k * 256 + t];
  h1[t] = (acc >= 0.0f) ? acc : 0.2f * acc;
  __syncthreads();
  acc = b1[t];
  for (int k = 0; k < 256; k++) acc += h1[k] * w1[k * 256 + t];
  h2[t] = (acc >= 0.0f) ? acc : 0.2f * acc;
  __syncthreads();
  float a6[6];
#pragma unroll
  for (int m = 0; m < 6; m++) a6[m] = b2[t + m * 256];
  for (int k = 0; k < 256; k++) {
    float h = h2[k];
#pragma unroll
    for (int m = 0; m < 6; m++) a6[m] += h * w2[k * 1536 + t + m * 256];
  }
#pragma unroll
  for (int m = 0; m < 6; m++) {
    int o = t + m * 256;
    if (o < 768) freqs[b * 768 + o] = a6[m] * 15.0f + 30.0f;
    else         phases[b * 768 + (o - 768)] = a6[m];
  }
}

// ---------------- coarse rays: perturbed z + transformed points --------------
__global__ __launch_bounds__(256) void k_rays(const float *c2w, float *zv, float *pts,
                                              unsigned kp0, unsigned kp1, int npts) {
  int e = blockIdx.x * 256 + threadIdx.x;
  if (e >= npts) return;
  int b = e / PPB, r = e % PPB, n = r / NS, s = r % NS;
  float dx, dy, dz; pixel_dir(n, dx, dy, dz);
  float delta = (1.12f - 0.88f) / 11.0f;
  float u = jax_uniform(kp0, kp1, (unsigned)e, (unsigned)npts);
  float zval = 0.88f + (float)s * delta + (u - 0.5f) * (float)(0.24 / 11.0);
  zv[e] = zval;
  float px = dx * zval, py = dy * zval, pz = dz * zval;
  const float *M = c2w + b * 16;
  float m[12];
#pragma unroll
  for (int i = 0; i < 12; i++) m[i] = M[i];
  pts[e * 3 + 0] = m[0] * px + m[1] * py + m[2] * pz + m[3];
  pts[e * 3 + 1] = m[4] * px + m[5] * py + m[6] * pz + m[7];
  pts[e * 3 + 2] = m[8] * px + m[9] * py + m[10] * pz + m[11];
}

// ---------------- SIREN forward v2 -------------------------------------------
// Block: 128 threads (2 waves), 64 points. Thread (g=t&31, h=t>>5) owns
// dims {4g..4g+3} x points {16h..16h+15}: per k-step 1 global float4 weight
// load + 4 ds_read_b128 + 64 FMA -> FMA-bound (was 8 ds_read : 32 FMA).
// xl[128][64] = 32KB exact (5 blocks/CU). XOR swizzle col = p ^ (((row>>2)&7)<<2)
// keeps 16B alignment, min-conflict writes, broadcast-clean reads.
__global__ __launch_bounds__(128) void k_siren(const float *pts, const float *freqs,
                                               const float *phases,
                                               const float *fw, const float *fb,
                                               const float *hw, const float *hb,
                                               const float *ow, const float *ob,
                                               float *outp) {
  __shared__ __align__(16) float xl[128 * 64];
  const int t = threadIdx.x;
  const int g = t & 31;        // dim group: dims 4g..4g+3
  const int h = t >> 5;        // point group: points 16h..16h+15
  const int base = blockIdx.x * 64;
  const int b = base / PPB;
  const int swz_w = (g & 7) << 2;   // write swizzle (same for rows 4g..4g+3)

  const float *fqb = freqs + b * 768;
  const float *phb = phases + b * 768;

  // ---- first layer: sin(freq * (pts @ fw + fb) + phase) ----
  {
    float pt[48];
    const float4 *ps = (const float4 *)(pts + (size_t)(base + 16 * h) * 3);
#pragma unroll
    for (int i = 0; i < 12; i++) ((float4 *)pt)[i] = ps[i];
    float4 fq = ((const float4 *)fqb)[g];
    float4 ph = ((const float4 *)phb)[g];
    float4 w0 = ((const float4 *)fw)[g];
    float4 w1 = ((const float4 *)(fw + 128))[g];
    float4 w2 = ((const float4 *)(fw + 256))[g];
    float4 bi = ((const float4 *)fb)[g];
#pragma unroll
    for (int q = 0; q < 4; q++) {
      float4 v0, v1, v2, v3;
      float *o0 = &v0.x, *o1 = &v1.x, *o2 = &v2.x, *o3 = &v3.x;
#pragma unroll
      for (int j = 0; j < 4; j++) {
        int p = 4 * q + j;
        float x = pt[3 * p], y = pt[3 * p + 1], z = pt[3 * p + 2];
        o0[j] = sinf(fq.x * (x * w0.x + y * w1.x + z * w2.x + bi.x) + ph.x);
        o1[j] = sinf(fq.y * (x * w0.y + y * w1.y + z * w2.y + bi.y) + ph.y);
        o2[j] = sinf(fq.z * (x * w0.z + y * w1.z + z * w2.z + bi.z) + ph.z);
        o3[j] = sinf(fq.w * (x * w0.w + y * w1.w + z * w2.w + bi.w) + ph.w);
      }
      int col = (16 * h + 4 * q) ^ swz_w;
      *((float4 *)&xl[(4 * g + 0) * 64 + col]) = v0;
      *((float4 *)&xl[(4 * g + 1) * 64 + col]) = v1;
      *((float4 *)&xl[(4 * g + 2) * 64 + col]) = v2;
      *((float4 *)&xl[(4 * g + 3) * 64 + col]) = v3;
    }
  }
  __syncthreads();

  // ---- hidden layers ----
#pragma unroll 1
  for (int L = 1; L < 6; L++) {
    float4 fq = ((const float4 *)(fqb + L * 128))[g];
    float4 ph = ((const float4 *)(phb + L * 128))[g];
    float4 bi = ((const float4 *)(hb + (L - 1) * 128))[g];
    const float4 *Wl = (const float4 *)(hw + (size_t)(L - 1) * 16384);
    float a0[16], a1[16], a2[16], a3[16];
#pragma unroll
    for (int p = 0; p < 16; p++) { a0[p] = bi.x; a1[p] = bi.y; a2[p] = bi.z; a3[p] = bi.w; }
#pragma unroll 4
    for (int k = 0; k < 128; k++) {
      float4 wv = Wl[k * 32 + g];
      int rb = k * 64;
      int swz = ((k >> 2) & 7) << 2;
#pragma unroll
      for (int q = 0; q < 4; q++) {
        float4 xv = *((const float4 *)&xl[rb + ((16 * h + 4 * q) ^ swz)]);
        a0[4 * q + 0] += xv.x * wv.x; a0[4 * q + 1] += xv.y * wv.x;
        a0[4 * q + 2] += xv.z * wv.x; a0[4 * q + 3] += xv.w * wv.x;
        a1[4 * q + 0] += xv.x * wv.y; a1[4 * q + 1] += xv.y * wv.y;
        a1[4 * q + 2] += xv.z * wv.y; a1[4 * q + 3] += xv.w * wv.y;
        a2[4 * q + 0] += xv.x * wv.z; a2[4 * q + 1] += xv.y * wv.z;
        a2[4 * q + 2] += xv.z * wv.z; a2[4 * q + 3] += xv.w * wv.z;
        a3[4 * q + 0] += xv.x * wv.w; a3[4 * q + 1] += xv.y * wv.w;
        a3[4 * q + 2] += xv.z * wv.w; a3[4 * q + 3] += xv.w * wv.w;
      }
    }
    __syncthreads();
#pragma unroll
    for (int q = 0; q < 4; q++) {
      float4 v0, v1, v2, v3;
      float *o0 = &v0.x, *o1 = &v1.x, *o2 = &v2.x, *o3 = &v3.x;
#pragma unroll
      for (int j = 0; j < 4; j++) {
        int p = 4 * q + j;
        o0[j] = sinf(fq.x * a0[p] + ph.x);
        o1[j] = sinf(fq.y * a1[p] + ph.y);
        o2[j] = sinf(fq.z * a2[p] + ph.z);
        o3[j] = sinf(fq.w * a3[p] + ph.w);
      }
      int col = (16 * h + 4 * q) ^ swz_w;
      *((float4 *)&xl[(4 * g + 0) * 64 + col]) = v0;
      *((float4 *)&xl[(4 * g + 1) * 64 + col]) = v1;
      *((float4 *)&xl[(4 * g + 2) * 64 + col]) = v2;
      *((float4 *)&xl[(4 * g + 3) * 64 + col]) = v3;
    }
    __syncthreads();
  }

  // ---- output layer: thread -> (point p = t>>1, channel pair c2 = t&1) ----
  {
    int p = t >> 1, c2 = t & 1;
    const float2 *ow2 = (const float2 *)ow;
    float2 a = ((const float2 *)ob)[c2];
#pragma unroll 4
    for (int k = 0; k < 128; k++) {
      float x = xl[k * 64 + (p ^ (((k >> 2) & 7) << 2))];
      float2 wv = ow2[k * 2 + c2];
      a.x += x * wv.x;
      a.y += x * wv.y;
    }
    if (c2 == 0) {
      a.x = 1.0f / (1.0f + expf(-a.x));
      a.y = 1.0f / (1.0f + expf(-a.y));
    } else {
      a.x = 1.0f / (1.0f + expf(-a.x));
    }
    *((float2 *)&outp[(size_t)(base + p) * 4 + 2 * c2]) = a;
  }
}

// ---------------- coarse weights -> sample_pdf -> fine points ----------------
__global__ __launch_bounds__(256) void k_pdf(const float *zv, const float *coutb,
                                             const float *c2w, float *fz, float *fpts,
                                             unsigned kq0, unsigned kq1, int nrays) {
  int ray = blockIdx.x * 256 + threadIdx.x;
  if (ray >= nrays) return;
  int b = ray / HW, n = ray % HW;
  float z[12];
#pragma unroll
  for (int s = 0; s < 12; s++) z[s] = zv[ray * 12 + s];
  float w[12]; float T = 1.0f;
#pragma unroll
  for (int s = 0; s < 12; s++) {
    float d = (s < 11) ? z[s + 1] - z[s] : 1e10f;
    float sg = coutb[(ray * 12 + s) * 4 + 3];
    float a = 1.0f - expf(-d * fmaxf(sg, 0.0f));
    w[s] = a * T;
    T *= 1.0f - a + 1e-10f;
  }
  float zmid[11];
#pragma unroll
  for (int i = 0; i < 11; i++) zmid[i] = 0.5f * (z[i] + z[i + 1]);
  float pw[10], sum = 0.0f;
#pragma unroll
  for (int i = 0; i < 10; i++) { pw[i] = w[i + 1] + 1e-5f; sum += pw[i]; }
  float cdf[11]; cdf[0] = 0.0f; float cacc = 0.0f;
#pragma unroll
  for (int i = 0; i < 10; i++) { cacc += pw[i] / sum; cdf[i + 1] = cacc; }

  const float *M = c2w + b * 16;
  float m[12];
#pragma unroll
  for (int i = 0; i < 12; i++) m[i] = M[i];
  float dx, dy, dz; pixel_dir(n, dx, dy, dz);
  float tdx = m[0] * dx + m[1] * dy + m[2] * dz;
  float tdy = m[4] * dx + m[5] * dy + m[6] * dz;
  float tdz = m[8] * dx + m[9] * dy + m[10] * dz;
  float ox = m[3], oy = m[7], oz = m[11];

#pragma unroll
  for (int t = 0; t < 12; t++) {
    float u = jax_uniform(kq0, kq1, (unsigned)(ray * 12 + t), (unsigned)(nrays * 12));
    int ind = 0;
#pragma unroll
    for (int i = 0; i < 11; i++) ind += (cdf[i] <= u) ? 1 : 0;  // searchsorted 'right'
    int below = ind - 1; below = below < 0 ? 0 : (below > 10 ? 10 : below);
    int above = ind > 10 ? 10 : ind;
    float cl = 0.f, ch = 0.f, blo = 0.f, bhi = 0.f;
#pragma unroll
    for (int i = 0; i < 11; i++) {
      if (i == below) { cl = cdf[i]; blo = zmid[i]; }
      if (i == above) { ch = cdf[i]; bhi = zmid[i]; }
    }
    float den = ch - cl; if (den < 1e-8f) den = 1.0f;
    float f = blo + (u - cl) / den * (bhi - blo);
    fz[ray * 12 + t] = f;
    fpts[(ray * 12 + t) * 3 + 0] = ox + tdx * f;
    fpts[(ray * 12 + t) * 3 + 1] = oy + tdy * f;
    fpts[(ray * 12 + t) * 3 + 2] = oz + tdz * f;
  }
}

// ---------------- merge (stable sort by z), final integration ----------------
__global__ __launch_bounds__(64) void k_final(const float *zv, const float *fz,
                                              const float *coutb, const float *foutb,
                                              float *outp, int B) {
  __shared__ float L[120 * 64];   // per-thread column: z[24], sig[24], rgb[3][24]
  __shared__ int inv[24 * 64];
  int t = threadIdx.x;
  int ray = blockIdx.x * 64 + t;
  int b = ray / HW, n = ray % HW;
#define SL(e) L[(e) * 64 + t]
  float zr[24];
#pragma unroll
  for (int s = 0; s < 12; s++) {
    float zfv = fz[ray * 12 + s], zcv = zv[ray * 12 + s];
    zr[s] = zfv; zr[12 + s] = zcv;   // concat order: fine first, then coarse
    SL(s) = zfv; SL(12 + s) = zcv;
    SL(24 + s)      = foutb[(ray * 12 + s) * 4 + 3];
    SL(24 + 12 + s) = coutb[(ray * 12 + s) * 4 + 3];
#pragma unroll
    for (int c = 0; c < 3; c++) {
      SL(48 + c * 24 + s)      = foutb[(ray * 12 + s) * 4 + c];
      SL(48 + c * 24 + 12 + s) = coutb[(ray * 12 + s) * 4 + c];
    }
  }
  // stable ranks (ties broken by original index) == JAX stable argsort
#pragma unroll
  for (int i = 0; i < 24; i++) {
    int rank = 0;
#pragma unroll
    for (int j = 0; j < 24; j++)
      rank += (zr[j] < zr[i] || (zr[j] == zr[i] && j < i)) ? 1 : 0;
    inv[rank * 64 + t] = i;
  }
  float Tacc = 1.0f, r0 = 0.f, r1 = 0.f, r2 = 0.f, df = 0.f;
  int icur = inv[0 * 64 + t];
  float zcur = SL(icur);
  for (int r = 0; r < 24; r++) {
    int inext = 0; float znext = 0.f;
    if (r < 23) { inext = inv[(r + 1) * 64 + t]; znext = SL(inext); }
    float d = (r < 23) ? znext - zcur : 1e10f;
    float sg = SL(24 + icur);
    float a = 1.0f - expf(-d * fmaxf(sg, 0.0f));
    float wt = a * Tacc;
    Tacc *= 1.0f - a + 1e-10f;
    r0 += wt * SL(48 + icur);
    r1 += wt * SL(48 + 24 + icur);
    r2 += wt * SL(48 + 48 + icur);
    df += wt * zcur;
    icur = inext; zcur = znext;
  }
#undef SL
  int pi = n >> 6, pj = n & 63;
  float x = -1.0f + (float)pj * (2.0f / 63.0f);
  float y =  1.0f - (float)pi * (2.0f / 63.0f);
  float zc = -1.0f / tanf(0.10471975511965978f);
  float invn = 1.0f / sqrtf(x * x + y * y + zc * zc);
  float mdz = -zc * invn;  // -rays_d.z (positive)
  outp[(b * 3 + 0) * HW + n] = r0 * 2.0f - 1.0f;
  outp[(b * 3 + 1) * HW + n] = r1 * 2.0f - 1.0f;
  outp[(b * 3 + 2) * HW + n] = r2 * 2.0f - 1.0f;
  outp[B * 3 * HW + ray] = df * mdz;
}

extern "C" void kernel_launch(void *const *d_in, const int *in_sizes, int n_in,
                              void *d_out, int out_size, void *d_ws, size_t ws_size,
                              hipStream_t stream) {
  const float *z   = (const float *)d_in[0];
  const float *c2w = (const float *)d_in[1];
  const float *mw0 = (const float *)d_in[2];
  const float *mb0 = (const float *)d_in[3];
  const float *mw1 = (const float *)d_in[4];
  const float *mb1 = (const float *)d_in[5];
  const float *mw2 = (const float *)d_in[6];
  const float *mb2 = (const float *)d_in[7];
  const float *fw  = (const float *)d_in[8];
  const float *fb  = (const float *)d_in[9];
  const float *hw  = (const float *)d_in[10];
  const float *hb  = (const float *)d_in[11];
  const float *ow  = (const float *)d_in[12];
  const float *ob  = (const float *)d_in[13];
  int B = in_sizes[0] / 256;
  int npts = B * PPB;
  int nrays = B * HW;

  float *ws     = (float *)d_ws;
  float *freqs  = ws;
  float *phases = freqs + (size_t)B * 768;
  float *zv     = phases + (size_t)B * 768;
  float *cpts   = zv + npts;
  float *coutb  = cpts + (size_t)npts * 3;
  float *fzv    = coutb + (size_t)npts * 4;
  float *fpts   = fzv + npts;
  float *foutb  = fpts + (size_t)npts * 3;

  // key(42) = [0,42]; split -> k_pert, k_pdf
  unsigned kp0, kp1, kq0, kq1;
#if JAX_PARTITIONABLE
  { unsigned o0, o1;
    tf2x32(0u, 42u, 0u, 0u, o0, o1); kp0 = o0; kp1 = o1;
    tf2x32(0u, 42u, 0u, 1u, o0, o1); kq0 = o0; kq1 = o1; }
#else
  { unsigned a0, a1, c0, c1;
    tf2x32(0u, 42u, 0u, 2u, a0, a1);
    tf2x32(0u, 42u, 1u, 3u, c0, c1);
    kp0 = a0; kp1 = c0; kq0 = a1; kq1 = c1; }
#endif

  k_map<<<B, 256, 0, stream>>>(z, mw0, mb0, mw1, mb1, mw2, mb2, freqs, phases);
  k_rays<<<(npts + 255) / 256, 256, 0, stream>>>(c2w, zv, cpts, kp0, kp1, npts);
  k_siren<<<npts / 64, 128, 0, stream>>>(cpts, freqs, phases, fw, fb, hw, hb, ow, ob, coutb);
  k_pdf<<<(nrays + 255) / 256, 256, 0, stream>>>(zv, coutb, c2w, fzv, fpts, kq0, kq1, nrays);
  k_siren<<<npts / 64, 128, 0, stream>>>(fpts, freqs, phases, fw, fb, hw, hb, ow, ob, foutb);
  k_final<<<nrays / 64, 64, 0, stream>>>(zv, fzv, coutb, foutb, (float *)d_out, B);
}